// Round 3
// baseline (77.133 us; speedup 1.0000x reference)
//
#include <hip/hip_runtime.h>

typedef float vfloat4 __attribute__((ext_vector_type(4)));

// ---------------------------------------------------------------------------
// Compile-time symbolic expansion: F = I + sum_{j=1..5} (A*dt)^j / j!
// with A*dt = C + x0*E (C, E constant 3x3). Every entry of F is a degree-<=5
// polynomial in x0 with constant coefficients, computed at compile time with
// the SAME recurrence order as the reference (term = term@M / j).
// ---------------------------------------------------------------------------
struct PolyMat {
    float c[3][3][6];  // c[i][j][k] = coeff of x0^k in F[i][j]
};

constexpr PolyMat compute_F() {
    constexpr float dt = 0.02f;
    float M[3][3][2] = {};
    M[0][0][0] = -10.0f * dt;
    M[0][1][0] =  10.0f * dt;
    M[1][0][0] =  28.0f * dt;
    M[1][1][0] =  -1.0f * dt;
    M[1][2][1] = -dt;            // -x0*dt
    M[2][1][1] =  dt;            //  x0*dt
    M[2][2][0] = (-8.0f / 3.0f) * dt;

    PolyMat F = {};
    float term[3][3][6] = {};
    for (int i = 0; i < 3; ++i) { term[i][i][0] = 1.0f; F.c[i][i][0] = 1.0f; }

    for (int j = 1; j <= 5; ++j) {
        float nt[3][3][6] = {};
        for (int i = 0; i < 3; ++i)
            for (int k = 0; k < 3; ++k)
                for (int m = 0; m < 3; ++m)
                    for (int d = 0; d < 6; ++d)
                        for (int e = 0; e < 2; ++e)
                            if (d + e < 6)
                                nt[i][k][d + e] += term[i][m][d] * M[m][k][e];
        for (int i = 0; i < 3; ++i)
            for (int k = 0; k < 3; ++k)
                for (int d = 0; d < 6; ++d) {
                    nt[i][k][d] /= (float)j;
                    term[i][k][d] = nt[i][k][d];
                    F.c[i][k][d] += nt[i][k][d];
                }
    }
    return F;
}

__device__ __forceinline__ float horner5(const float c[6], float x) {
    float p = c[5];
    p = fmaf(p, x, c[4]);
    p = fmaf(p, x, c[3]);
    p = fmaf(p, x, c[2]);
    p = fmaf(p, x, c[1]);
    p = fmaf(p, x, c[0]);
    return p;
}

// Block: 256 threads, 4 elements/thread = 1024 elements = 3072 floats = 768 float4.
// Global loads/stores are fully coalesced float4; LDS redistributes to the
// 3-floats-per-element layout each thread needs.
__global__ __launch_bounds__(256) void lorenz_kernel(const float* __restrict__ x,
                                                     float* __restrict__ out, int V /* total float4 count */) {
    constexpr PolyMat F = compute_F();
    __shared__ float lds[3072];

    const int tid = threadIdx.x;
    const int vecBase = blockIdx.x * 768;
    const vfloat4* __restrict__ xv = (const vfloat4*)x;
    vfloat4* __restrict__ ov = (vfloat4*)out;

    // Phase 1: coalesced global -> LDS (linear layout)
    vfloat4 in[3];
#pragma unroll
    for (int i = 0; i < 3; ++i) {
        const int v = vecBase + i * 256 + tid;
        in[i] = (v < V) ? __builtin_nontemporal_load(&xv[v]) : (vfloat4){0.f, 0.f, 0.f, 0.f};
    }
#pragma unroll
    for (int i = 0; i < 3; ++i)
        ((vfloat4*)lds)[i * 256 + tid] = in[i];
    __syncthreads();

    // Phase 2: each thread owns LDS words [12*tid, 12*tid+12) — its 4 elements.
    // Reads and (later) writes touch ONLY its own region -> no sync needed
    // between read and write-back.
    float xs[12];
    vfloat4* myslot = (vfloat4*)(lds + tid * 12);
#pragma unroll
    for (int i = 0; i < 3; ++i) {
        vfloat4 t = myslot[i];
        xs[i * 4 + 0] = t.x; xs[i * 4 + 1] = t.y; xs[i * 4 + 2] = t.z; xs[i * 4 + 3] = t.w;
    }

    float os[12];
#pragma unroll
    for (int e = 0; e < 4; ++e) {
        const float x0 = xs[e * 3 + 0];
        const float x1 = xs[e * 3 + 1];
        const float x2 = xs[e * 3 + 2];
        const float f00 = horner5(F.c[0][0], x0), f01 = horner5(F.c[0][1], x0), f02 = horner5(F.c[0][2], x0);
        const float f10 = horner5(F.c[1][0], x0), f11 = horner5(F.c[1][1], x0), f12 = horner5(F.c[1][2], x0);
        const float f20 = horner5(F.c[2][0], x0), f21 = horner5(F.c[2][1], x0), f22 = horner5(F.c[2][2], x0);
        os[e * 3 + 0] = fmaf(f02, x2, fmaf(f01, x1, f00 * x0));
        os[e * 3 + 1] = fmaf(f12, x2, fmaf(f11, x1, f10 * x0));
        os[e * 3 + 2] = fmaf(f22, x2, fmaf(f21, x1, f20 * x0));
    }

#pragma unroll
    for (int i = 0; i < 3; ++i)
        myslot[i] = (vfloat4){os[i * 4 + 0], os[i * 4 + 1], os[i * 4 + 2], os[i * 4 + 3]};
    __syncthreads();

    // Phase 3: coalesced LDS -> global (nontemporal streaming store, 24 MB)
#pragma unroll
    for (int i = 0; i < 3; ++i) {
        const int v = vecBase + i * 256 + tid;
        if (v < V) {
            vfloat4 t = ((vfloat4*)lds)[i * 256 + tid];
            __builtin_nontemporal_store(t, &ov[v]);
        }
    }
}

extern "C" void kernel_launch(void* const* d_in, const int* in_sizes, int n_in,
                              void* d_out, int out_size, void* d_ws, size_t ws_size,
                              hipStream_t stream) {
    const float* x = (const float*)d_in[0];
    float* out = (float*)d_out;
    const int total_floats = in_sizes[0];     // 6,000,000 (divisible by 4)
    const int V = total_floats / 4;           // float4 count = 1,500,000
    const int vecs_per_block = 768;
    const int grid = (V + vecs_per_block - 1) / vecs_per_block;
    lorenz_kernel<<<grid, 256, 0, stream>>>(x, out, V);
}